// Round 5
// baseline (662.454 us; speedup 1.0000x reference)
//
#include <hip/hip_runtime.h>

typedef __attribute__((ext_vector_type(4))) float f32x4;
typedef __attribute__((ext_vector_type(8))) short bf16x8;
typedef __attribute__((ext_vector_type(4))) short s16x4;

__device__ __forceinline__ short f2bf(float f) {
  union { float f; unsigned u; } x; x.f = f;
  return (short)((x.u + 0x7fffu + ((x.u >> 16) & 1u)) >> 16);   // RNE
}

__device__ __forceinline__ bf16x8 pack8(float4 a, float4 b) {
  bf16x8 v;
  v[0] = f2bf(a.x); v[1] = f2bf(a.y); v[2] = f2bf(a.z); v[3] = f2bf(a.w);
  v[4] = f2bf(b.x); v[5] = f2bf(b.y); v[6] = f2bf(b.z); v[7] = f2bf(b.w);
  return v;
}

// ---------------- prep: weights->bf16, q padded->bf16, bias [8][64][64] -----
__global__ __launch_bounds__(256) void prep_kernel(
    const float* __restrict__ qkv_w, const float* __restrict__ proj_w,
    const float* __restrict__ qg, const float* __restrict__ table,
    short* __restrict__ wq_b, short* __restrict__ wp_b,
    short* __restrict__ q_b, float* __restrict__ biasg)
{
  int idx = blockIdx.x * 256 + threadIdx.x;
  if (idx < 131072) { wq_b[idx] = f2bf(qkv_w[idx]); return; }
  idx -= 131072;
  if (idx < 65536) { wp_b[idx] = f2bf(proj_w[idx]); return; }
  idx -= 65536;
  if (idx < 1048576) {                       // q padded: [64 win][8 h][64 n][32 d]
    int d = idx & 31, n = (idx >> 5) & 63, hh = (idx >> 11) & 7, w = idx >> 14;
    float v = (n < 49) ? qg[((w * 8 + hh) * 49 + n) * 32 + d] : 0.f;
    q_b[idx] = f2bf(v);
    return;
  }
  idx -= 1048576;
  if (idx < 32768) {                         // bias padded: [8 h][64 q][64 k]
    int hh = idx >> 12, rem = idx & 4095;
    int q = rem >> 6, k = rem & 63;
    float v = 0.f;
    if (q < 49 && k < 49) {
      int di = q / 7 - k / 7 + 6, dj = q % 7 - k % 7 + 6;
      v = table[(di * 13 + dj) * 8 + hh];
    }
    biasg[idx] = v;
  }
}

// ---------------- fused per-window kernel -----------------------------------
// block = 1 window, 1024 threads = 16 waves. 1 block/CU is pinned by regs
// (92+ unified VGPR+AGPR -> max 16 waves/CU, m69), so LDS is free up to 160K:
// use 128 KiB with DEDICATED P and Ol regions -> only TWO barriers total.
// Phase-1 A-operands come straight from global x (f32->bf16 cvt); no As stage.
// LDS:MFMA read ratio is 1:4 in both GEMM phases (64-col / 32-col strips).
__global__ __launch_bounds__(1024, 4) void fused_win(
    const float* __restrict__ x, const short* __restrict__ q_b,
    const short* __restrict__ wq_b, const short* __restrict__ wp_b,
    const float* __restrict__ qkv_b, const float* __restrict__ proj_b,
    const float* __restrict__ biasg, float* __restrict__ out)
{
  __shared__ __align__(16) char smem[131072];         // 128 KiB
  short* Kl = (short*)smem;                           // [64 key][256 c]
  short* vT = (short*)(smem + 32768);                 // [256 d][64 key]
  short* Ol = (short*)(smem + 98304);                 // [64 q][256 c]
  // per-wave P bounce: smem + 65536 + w*2048  ([32 q][32 k], dedicated)

  const int tid = threadIdx.x;
  const int b   = blockIdx.x;
  const int lane = tid & 63;
  const int w   = tid >> 6;        // 0..15
  const int lr  = lane & 15;
  const int lg  = lane >> 4;

  const float* xsrc = x + (long)b * 49 * 256;

  // -- phase 1: kv = x @ qkv_w^T; A-frags direct from global x --------------
  // waves 0-7 (K, swapped): (cg = 64-col group, rh = row half) -> acc rows=c
  // waves 8-15 (V, normal): acc rows=key, cols=d
  const bool isK = (w < 8);
  const int cg = (w & 7) >> 1;     // 0..3
  const int rh = w & 1;            // 0..1
  f32x4 acc[8] = {};
  const short* wbase = wq_b + ((isK ? 0 : 256) + cg * 64) * 256;

  #pragma unroll 2
  for (int kk = 0; kk < 8; ++kk) {
    bf16x8 xa[2], wf[4];
    #pragma unroll
    for (int t = 0; t < 2; ++t) {
      int row = rh * 32 + t * 16 + lr;
      if (row < 49) {
        const float4* p = (const float4*)(xsrc + row * 256 + kk * 32 + lg * 8);
        xa[t] = pack8(p[0], p[1]);
      } else {
        #pragma unroll
        for (int j = 0; j < 8; ++j) xa[t][j] = 0;
      }
    }
    #pragma unroll
    for (int s = 0; s < 4; ++s)
      wf[s] = *(const bf16x8*)(wbase + (s * 16 + lr) * 256 + kk * 32 + lg * 8);
    __builtin_amdgcn_s_setprio(1);
    if (isK) {
      #pragma unroll
      for (int s = 0; s < 4; ++s)
        #pragma unroll
        for (int t = 0; t < 2; ++t)
          acc[s * 2 + t] = __builtin_amdgcn_mfma_f32_16x16x32_bf16(wf[s], xa[t], acc[s * 2 + t], 0, 0, 0);
    } else {
      #pragma unroll
      for (int t = 0; t < 2; ++t)
        #pragma unroll
        for (int s = 0; s < 4; ++s)
          acc[t * 4 + s] = __builtin_amdgcn_mfma_f32_16x16x32_bf16(xa[t], wf[s], acc[t * 4 + s], 0, 0, 0);
    }
    __builtin_amdgcn_s_setprio(0);
  }

  // epilogue: +qkv_b, b64 swizzled LDS writes
  if (isK) {         // lane: c = cg*64+s*16+lg*4+r, key = rh*32+t*16+lr
    #pragma unroll
    for (int s = 0; s < 4; ++s) {
      int c0 = cg * 64 + s * 16 + lg * 4;
      float4 bv = *(const float4*)(qkv_b + c0);
      #pragma unroll
      for (int t = 0; t < 2; ++t) {
        int key = rh * 32 + t * 16 + lr;
        s16x4 sv;
        sv[0] = f2bf(acc[s * 2 + t][0] + bv.x);
        sv[1] = f2bf(acc[s * 2 + t][1] + bv.y);
        sv[2] = f2bf(acc[s * 2 + t][2] + bv.z);
        sv[3] = f2bf(acc[s * 2 + t][3] + bv.w);
        *(s16x4*)(&Kl[key * 256 + ((((c0 >> 3) ^ (key & 7)) << 3)) + (c0 & 7)]) = sv;
      }
    }
  } else {           // lane: key = rh*32+t*16+lg*4+r, d = cg*64+s*16+lr
    #pragma unroll
    for (int s = 0; s < 4; ++s) {
      int d = cg * 64 + s * 16 + lr;
      float bv = qkv_b[256 + d];
      #pragma unroll
      for (int t = 0; t < 2; ++t) {
        int key0 = rh * 32 + t * 16 + lg * 4;
        s16x4 sv;
        sv[0] = f2bf(acc[t * 4 + s][0] + bv);
        sv[1] = f2bf(acc[t * 4 + s][1] + bv);
        sv[2] = f2bf(acc[t * 4 + s][2] + bv);
        sv[3] = f2bf(acc[t * 4 + s][3] + bv);
        *(s16x4*)(&vT[d * 64 + ((((key0 >> 3) ^ (d & 7)) << 3)) + (key0 & 7)]) = sv;
      }
    }
  }
  __syncthreads();                                    // BARRIER 1 (kv ready)

  // -- phase 2: S^T = mfma(K, Q); wave = (head h, q-half qh) ----------------
  const int h = w >> 1, qh = w & 1;
  f32x4 st[4][2] = {};                                // st[kt][qt]
  {
    const short* qsrc = q_b + ((long)(b >> 6) * 8 + h) * 2048 + qh * 1024;
    bf16x8 qa[2], kb[4];
    #pragma unroll
    for (int qt = 0; qt < 2; ++qt)
      qa[qt] = *(const bf16x8*)(qsrc + (qt * 16 + lr) * 32 + lg * 8);
    #pragma unroll
    for (int kt = 0; kt < 4; ++kt) {
      int key = kt * 16 + lr;
      kb[kt] = *(const bf16x8*)(&Kl[key * 256 + (((h * 4 + lg) ^ (key & 7)) << 3)]);
    }
    __builtin_amdgcn_s_setprio(1);
    #pragma unroll
    for (int kt = 0; kt < 4; ++kt)
      #pragma unroll
      for (int qt = 0; qt < 2; ++qt)
        st[kt][qt] = __builtin_amdgcn_mfma_f32_16x16x32_bf16(kb[kt], qa[qt], st[kt][qt], 0, 0, 0);
    __builtin_amdgcn_s_setprio(0);
  }

  // -- phase 3: softmax; row q = qh*32+qt*16+lr, keys in-lane (2 shfls) -----
  {
    const float* bh = biasg + h * 4096;
    const float sc = 0.17677669529663687f;            // 32^-0.5
    #pragma unroll
    for (int qt = 0; qt < 2; ++qt) {
      int q = qh * 32 + qt * 16 + lr;
      float mx = -1e30f;
      #pragma unroll
      for (int kt = 0; kt < 4; ++kt) {
        int key0 = kt * 16 + lg * 4;
        float4 bv = *(const float4*)(bh + q * 64 + key0);
        #pragma unroll
        for (int r = 0; r < 4; ++r) {
          float t = st[kt][qt][r] * sc + ((r == 0) ? bv.x : (r == 1) ? bv.y : (r == 2) ? bv.z : bv.w);
          if (key0 + r >= 49) t = -1e30f;
          st[kt][qt][r] = t;
          mx = fmaxf(mx, t);
        }
      }
      mx = fmaxf(mx, __shfl_xor(mx, 16));
      mx = fmaxf(mx, __shfl_xor(mx, 32));
      float sum = 0.f;
      #pragma unroll
      for (int kt = 0; kt < 4; ++kt)
        #pragma unroll
        for (int r = 0; r < 4; ++r) {
          float e = __expf(st[kt][qt][r] - mx);
          st[kt][qt][r] = e; sum += e;
        }
      sum += __shfl_xor(sum, 16);
      sum += __shfl_xor(sum, 32);
      float rinv = 1.f / sum;                         // fold 1/sum into P
      #pragma unroll
      for (int kt = 0; kt < 4; ++kt)
        #pragma unroll
        for (int r = 0; r < 4; ++r) st[kt][qt][r] *= rinv;
    }
  }

  // -- phase 4: O^T = mfma(V^T, P^T); P via DEDICATED per-wave LDS ----------
  short* Pw = (short*)(smem + 65536 + w * 2048);      // [32 q][32 k]
  f32x4 o[2][2] = {};                                 // o[dt][qt]
  #pragma unroll
  for (int ks = 0; ks < 2; ++ks) {
    #pragma unroll
    for (int kh = 0; kh < 2; ++kh) {
      int kt = ks * 2 + kh;
      int kloc0 = kh * 16 + lg * 4;
      #pragma unroll
      for (int qt = 0; qt < 2; ++qt) {
        int qloc = qt * 16 + lr;
        s16x4 sv;
        sv[0] = f2bf(st[kt][qt][0]);
        sv[1] = f2bf(st[kt][qt][1]);
        sv[2] = f2bf(st[kt][qt][2]);
        sv[3] = f2bf(st[kt][qt][3]);
        *(s16x4*)(&Pw[qloc * 32 + ((((kloc0 >> 3) ^ ((qloc >> 1) & 3)) << 3)) + (kloc0 & 7)]) = sv;
      }
    }
    bf16x8 pa[2], vb[2];
    #pragma unroll
    for (int qt = 0; qt < 2; ++qt) {
      int qloc = qt * 16 + lr;
      pa[qt] = *(const bf16x8*)(&Pw[qloc * 32 + ((lg ^ ((qloc >> 1) & 3)) << 3)]);
    }
    #pragma unroll
    for (int dt = 0; dt < 2; ++dt) {
      int d = h * 32 + dt * 16 + lr;
      vb[dt] = *(const bf16x8*)(&vT[d * 64 + (((ks * 4 + lg) ^ (d & 7)) << 3)]);
    }
    __builtin_amdgcn_s_setprio(1);
    #pragma unroll
    for (int dt = 0; dt < 2; ++dt)
      #pragma unroll
      for (int qt = 0; qt < 2; ++qt)
        o[dt][qt] = __builtin_amdgcn_mfma_f32_16x16x32_bf16(vb[dt], pa[qt], o[dt][qt], 0, 0, 0);
    __builtin_amdgcn_s_setprio(0);
  }

  // -- phase 5: O^T -> Ol[q][c] (dedicated region, b64 writes) --------------
  #pragma unroll
  for (int dt = 0; dt < 2; ++dt) {
    int c0 = h * 32 + dt * 16 + lg * 4;
    #pragma unroll
    for (int qt = 0; qt < 2; ++qt) {
      int q = qh * 32 + qt * 16 + lr;
      s16x4 sv;
      sv[0] = f2bf(o[dt][qt][0]);
      sv[1] = f2bf(o[dt][qt][1]);
      sv[2] = f2bf(o[dt][qt][2]);
      sv[3] = f2bf(o[dt][qt][3]);
      *(s16x4*)(&Ol[q * 256 + ((((c0 >> 3) ^ (q & 7)) << 3)) + (c0 & 7)]) = sv;
    }
  }
  __syncthreads();                                    // BARRIER 2 (Ol ready)

  // -- phase 6: out = O @ proj_w^T + proj_b; wave = (32-col strip cs, qh) ---
  const int cs = w >> 1;                              // 0..7
  f32x4 po[2][2] = {};                                // po[mt][qt]
  const short* wpb = wp_b + (cs * 32) * 256;
  #pragma unroll 2
  for (int kk = 0; kk < 8; ++kk) {
    bf16x8 of[2], wf2[2];
    #pragma unroll
    for (int qt = 0; qt < 2; ++qt) {
      int q = qh * 32 + qt * 16 + lr;
      of[qt] = *(const bf16x8*)(&Ol[q * 256 + (((kk * 4 + lg) ^ (q & 7)) << 3)]);
    }
    #pragma unroll
    for (int mt = 0; mt < 2; ++mt)
      wf2[mt] = *(const bf16x8*)(wpb + (mt * 16 + lr) * 256 + kk * 32 + lg * 8);
    __builtin_amdgcn_s_setprio(1);
    #pragma unroll
    for (int mt = 0; mt < 2; ++mt)
      #pragma unroll
      for (int qt = 0; qt < 2; ++qt)
        po[mt][qt] = __builtin_amdgcn_mfma_f32_16x16x32_bf16(wf2[mt], of[qt], po[mt][qt], 0, 0, 0);
    __builtin_amdgcn_s_setprio(0);
  }
  float* od = out + (long)b * 49 * 256;
  #pragma unroll
  for (int mt = 0; mt < 2; ++mt) {
    int c0 = cs * 32 + mt * 16 + lg * 4;
    float4 pb = *(const float4*)(proj_b + c0);
    #pragma unroll
    for (int qt = 0; qt < 2; ++qt) {
      int q = qh * 32 + qt * 16 + lr;
      if (q < 49) {
        float4 ov;
        ov.x = po[mt][qt][0] + pb.x;
        ov.y = po[mt][qt][1] + pb.y;
        ov.z = po[mt][qt][2] + pb.z;
        ov.w = po[mt][qt][3] + pb.w;
        *(float4*)(od + q * 256 + c0) = ov;
      }
    }
  }
}

extern "C" void kernel_launch(void* const* d_in, const int* in_sizes, int n_in,
                              void* d_out, int out_size, void* d_ws, size_t ws_size,
                              hipStream_t stream) {
  const float* x      = (const float*)d_in[0];
  const float* qg     = (const float*)d_in[1];
  const float* qkv_w  = (const float*)d_in[2];
  const float* qkv_b  = (const float*)d_in[3];
  const float* proj_w = (const float*)d_in[4];
  const float* proj_b = (const float*)d_in[5];
  const float* table  = (const float*)d_in[6];
  float* out = (float*)d_out;

  char* ws = (char*)d_ws;                 // total scratch: ~2.62 MB
  short* wq_b  = (short*)ws;              // 262144 B  bf16 qkv_w [512][256]
  short* wp_b  = (short*)(ws + 262144);   // 131072 B  bf16 proj_w [256][256]
  short* q_b   = (short*)(ws + 393216);   // 2097152 B bf16 q padded [64][8][64][32]
  float* biasg = (float*)(ws + 2490368);  // 131072 B  f32 bias padded [8][64][64]

  const int prep_total = 131072 + 65536 + 1048576 + 32768;
  prep_kernel<<<(prep_total + 255) / 256, 256, 0, stream>>>(
      qkv_w, proj_w, qg, table, wq_b, wp_b, q_b, biasg);
  fused_win<<<4096, 1024, 0, stream>>>(x, q_b, wq_b, wp_b, qkv_b, proj_b, biasg, out);
}

// Round 6
// 360.228 us; speedup vs baseline: 1.8390x; 1.8390x over previous
//
#include <hip/hip_runtime.h>

typedef __attribute__((ext_vector_type(4))) float f32x4;
typedef __attribute__((ext_vector_type(8))) short bf16x8;
typedef __attribute__((ext_vector_type(4))) short s16x4;

__device__ __forceinline__ short f2bf(float f) {
  union { float f; unsigned u; } x; x.f = f;
  return (short)((x.u + 0x7fffu + ((x.u >> 16) & 1u)) >> 16);   // RNE
}

__device__ __forceinline__ bf16x8 pack8(float4 a, float4 b) {
  bf16x8 v;
  v[0] = f2bf(a.x); v[1] = f2bf(a.y); v[2] = f2bf(a.z); v[3] = f2bf(a.w);
  v[4] = f2bf(b.x); v[5] = f2bf(b.y); v[6] = f2bf(b.z); v[7] = f2bf(b.w);
  return v;
}

// ---- prep1: Wv->bf16, Wp->bf16, Wk^T->bf16, bias expand [8][64][64] --------
__global__ __launch_bounds__(256) void prep1(
    const float* __restrict__ qkv_w, const float* __restrict__ proj_w,
    const float* __restrict__ table,
    short* __restrict__ wv_b, short* __restrict__ wp_b,
    short* __restrict__ wkT_b, float* __restrict__ biasg)
{
  int idx = blockIdx.x * 256 + threadIdx.x;
  if (idx < 65536) { wv_b[idx] = f2bf(qkv_w[65536 + idx]); return; }   // rows 256..511
  idx -= 65536;
  if (idx < 65536) { wp_b[idx] = f2bf(proj_w[idx]); return; }
  idx -= 65536;
  if (idx < 65536) {                         // wkT[j][c] = qkv_w[c][j], c<256
    int j = idx >> 8, c = idx & 255;
    wkT_b[j * 256 + c] = f2bf(qkv_w[c * 256 + j]);
    return;
  }
  idx -= 65536;
  if (idx < 32768) {                         // bias padded: [8 h][64 q][64 k]
    int hh = idx >> 12, rem = idx & 4095;
    int q = rem >> 6, k = rem & 63;
    float v = 0.f;
    if (q < 49 && k < 49) {
      int di = q / 7 - k / 7 + 6, dj = q % 7 - k % 7 + 6;
      v = table[(di * 13 + dj) * 8 + hh];
    }
    biasg[idx] = v;
  }
}

// ---- prep2: q-tilde = (q*scale) @ Wk  -> [64bg][8h][64q][256j] bf16 --------
// One wave per (jc 64-col chunk, h, bg). Swapped mfma -> b64 [q][j] writes.
__global__ __launch_bounds__(64) void prep2(
    const float* __restrict__ qg, const short* __restrict__ wkT_b,
    short* __restrict__ qt_b)
{
  const int lane = threadIdx.x, lr = lane & 15, lg = lane >> 4;
  const int jc = blockIdx.x, h = blockIdx.y, bg = blockIdx.z;
  const float sc = 0.17677669529663687f;     // 32^-0.5, folded here

  bf16x8 a[4], qb[4];
  #pragma unroll
  for (int jt = 0; jt < 4; ++jt)
    a[jt] = *(const bf16x8*)(wkT_b + (jc * 64 + jt * 16 + lr) * 256 + h * 32 + lg * 8);
  const float* qs = qg + ((long)(bg * 8 + h) * 49) * 32;
  #pragma unroll
  for (int nt = 0; nt < 4; ++nt) {
    int q = nt * 16 + lr;
    if (q < 49) {
      const float4* p = (const float4*)(qs + q * 32 + lg * 8);
      float4 f0 = p[0], f1 = p[1];
      f0.x *= sc; f0.y *= sc; f0.z *= sc; f0.w *= sc;
      f1.x *= sc; f1.y *= sc; f1.z *= sc; f1.w *= sc;
      qb[nt] = pack8(f0, f1);
    } else {
      #pragma unroll
      for (int j = 0; j < 8; ++j) qb[nt][j] = 0;
    }
  }
  f32x4 acc[4][4] = {};
  #pragma unroll
  for (int jt = 0; jt < 4; ++jt)
    #pragma unroll
    for (int nt = 0; nt < 4; ++nt)
      acc[jt][nt] = __builtin_amdgcn_mfma_f32_16x16x32_bf16(a[jt], qb[nt], acc[jt][nt], 0, 0, 0);
  short* dst = qt_b + ((long)(bg * 8 + h) * 64) * 256;
  #pragma unroll
  for (int jt = 0; jt < 4; ++jt) {
    int j0 = jc * 64 + jt * 16 + lg * 4;
    #pragma unroll
    for (int nt = 0; nt < 4; ++nt) {
      int q = nt * 16 + lr;
      s16x4 sv;
      sv[0] = f2bf(acc[jt][nt][0]); sv[1] = f2bf(acc[jt][nt][1]);
      sv[2] = f2bf(acc[jt][nt][2]); sv[3] = f2bf(acc[jt][nt][3]);
      *(s16x4*)(dst + q * 256 + j0) = sv;
    }
  }
}

// ---- fused: block = 1 window, 512 thr = 8 waves = 8 heads ------------------
// LDS 64KB -> 2 blocks/CU. Waves independent between B1 and B2 (3 barriers).
// S = q~ . x^T (K never materialized); k-bias dropped (softmax row-const);
// v-bias folded at Ol write (sum P = 1). Per-wave 4KB scratch: v^T then P.
__global__ __launch_bounds__(512, 4) void fused_win(
    const float* __restrict__ x, const short* __restrict__ qt_b,
    const short* __restrict__ wv_b, const short* __restrict__ wp_b,
    const float* __restrict__ qkv_b, const float* __restrict__ proj_b,
    const float* __restrict__ biasg, float* __restrict__ out)
{
  __shared__ __align__(16) char smem[65536];
  short* As = (short*)smem;                       // [64][256] bf16, swizzled
  short* Ol = (short*)smem;                       // aliases As (dead after B2)
  const int tid = threadIdx.x, b = blockIdx.x;
  const int lane = tid & 63, w = tid >> 6;        // w = head 0..7
  const int lr = lane & 15, lg = lane >> 4;
  short* scr = (short*)(smem + 32768 + w * 4096); // private 4KB: v^T then P

  // -- stage x (f32 -> bf16), rows 49..63 zero ------------------------------
  const float* xsrc = x + (long)b * 49 * 256;
  #pragma unroll
  for (int it = 0; it < 4; ++it) {
    int slot = it * 512 + tid;
    int row = slot >> 5, s = slot & 31;
    bf16x8 v;
    if (row < 49) {
      const float4* p = (const float4*)(xsrc + row * 256 + s * 8);
      v = pack8(p[0], p[1]);
    } else {
      #pragma unroll
      for (int j = 0; j < 8; ++j) v[j] = 0;
    }
    *(bf16x8*)(&As[row * 256 + ((s ^ (row & 7)) << 3)]) = v;
  }
  __syncthreads();                                // B1

  // -- v-GEMM: v_h = x @ Wv_h^T (no bias), D rows=key cols=d ----------------
  f32x4 va[8] = {};
  {
    const short* wvb = wv_b + (w * 32) * 256;
    #pragma unroll 2
    for (int kk = 0; kk < 8; ++kk) {
      bf16x8 xa[4];
      #pragma unroll
      for (int mt = 0; mt < 4; ++mt) {
        int row = mt * 16 + lr;
        xa[mt] = *(const bf16x8*)(&As[row * 256 + (((kk * 4 + lg) ^ (row & 7)) << 3)]);
      }
      __builtin_amdgcn_s_setprio(1);
      #pragma unroll
      for (int nt = 0; nt < 2; ++nt) {
        bf16x8 wf = *(const bf16x8*)(wvb + (nt * 16 + lr) * 256 + kk * 32 + lg * 8);
        #pragma unroll
        for (int mt = 0; mt < 4; ++mt)
          va[mt * 2 + nt] = __builtin_amdgcn_mfma_f32_16x16x32_bf16(xa[mt], wf, va[mt * 2 + nt], 0, 0, 0);
      }
      __builtin_amdgcn_s_setprio(0);
    }
  }
  // v^T -> scr [32d][64key] (b64, swizzled)
  #pragma unroll
  for (int nt = 0; nt < 2; ++nt) {
    int d = nt * 16 + lr;
    #pragma unroll
    for (int mt = 0; mt < 4; ++mt) {
      int key0 = mt * 16 + lg * 4;
      s16x4 sv;
      sv[0] = f2bf(va[mt * 2 + nt][0]); sv[1] = f2bf(va[mt * 2 + nt][1]);
      sv[2] = f2bf(va[mt * 2 + nt][2]); sv[3] = f2bf(va[mt * 2 + nt][3]);
      *(s16x4*)(&scr[d * 64 + ((((key0 >> 3) ^ (d & 7)) << 3)) + (key0 & 7)]) = sv;
    }
  }

  // -- S-GEMM: S^T = x . q~^T  (K=256), D rows=key cols=q -------------------
  f32x4 st[4][4] = {};
  {
    const short* qbh = qt_b + ((long)((b >> 6) * 8 + w) * 64) * 256;
    #pragma unroll 2
    for (int kk = 0; kk < 8; ++kk) {
      bf16x8 xa[4];
      #pragma unroll
      for (int mt = 0; mt < 4; ++mt) {
        int row = mt * 16 + lr;
        xa[mt] = *(const bf16x8*)(&As[row * 256 + (((kk * 4 + lg) ^ (row & 7)) << 3)]);
      }
      __builtin_amdgcn_s_setprio(1);
      #pragma unroll
      for (int nt = 0; nt < 4; ++nt) {
        bf16x8 qf = *(const bf16x8*)(qbh + (nt * 16 + lr) * 256 + kk * 32 + lg * 8);
        #pragma unroll
        for (int mt = 0; mt < 4; ++mt)
          st[mt][nt] = __builtin_amdgcn_mfma_f32_16x16x32_bf16(xa[mt], qf, st[mt][nt], 0, 0, 0);
      }
      __builtin_amdgcn_s_setprio(0);
    }
  }

  // -- softmax (scale pre-folded in q~); key = mt*16+lg*4+r, q = nt*16+lr ---
  {
    const float* bh = biasg + w * 4096;
    #pragma unroll
    for (int nt = 0; nt < 4; ++nt) {
      int q = nt * 16 + lr;
      float mx = -1e30f;
      #pragma unroll
      for (int mt = 0; mt < 4; ++mt) {
        int key0 = mt * 16 + lg * 4;
        float4 bv = *(const float4*)(bh + q * 64 + key0);
        #pragma unroll
        for (int r = 0; r < 4; ++r) {
          float t = st[mt][nt][r] + ((r == 0) ? bv.x : (r == 1) ? bv.y : (r == 2) ? bv.z : bv.w);
          if (key0 + r >= 49) t = -1e30f;
          st[mt][nt][r] = t;
          mx = fmaxf(mx, t);
        }
      }
      mx = fmaxf(mx, __shfl_xor(mx, 16));
      mx = fmaxf(mx, __shfl_xor(mx, 32));
      float sum = 0.f;
      #pragma unroll
      for (int mt = 0; mt < 4; ++mt)
        #pragma unroll
        for (int r = 0; r < 4; ++r) {
          float e = __expf(st[mt][nt][r] - mx);
          st[mt][nt][r] = e; sum += e;
        }
      sum += __shfl_xor(sum, 16);
      sum += __shfl_xor(sum, 32);
      float rinv = 1.f / sum;
      #pragma unroll
      for (int mt = 0; mt < 4; ++mt)
        #pragma unroll
        for (int r = 0; r < 4; ++r) st[mt][nt][r] *= rinv;
    }
  }

  // -- pull V^T fragments to regs BEFORE P overwrites scr -------------------
  bf16x8 vb[4];
  #pragma unroll
  for (int dt = 0; dt < 2; ++dt) {
    int d = dt * 16 + lr;
    #pragma unroll
    for (int ks = 0; ks < 2; ++ks)
      vb[dt * 2 + ks] = *(const bf16x8*)(&scr[d * 64 + (((ks * 4 + lg) ^ (d & 7)) << 3)]);
  }

  // -- PV: O^T = V^T . P^T, P chunked through scr [64q][32kloc] -------------
  f32x4 o[2][4] = {};
  #pragma unroll
  for (int ks = 0; ks < 2; ++ks) {
    #pragma unroll
    for (int mh = 0; mh < 2; ++mh) {
      int mt = ks * 2 + mh;
      int kloc0 = mh * 16 + lg * 4;
      #pragma unroll
      for (int nt = 0; nt < 4; ++nt) {
        int q = nt * 16 + lr;
        s16x4 sv;
        sv[0] = f2bf(st[mt][nt][0]); sv[1] = f2bf(st[mt][nt][1]);
        sv[2] = f2bf(st[mt][nt][2]); sv[3] = f2bf(st[mt][nt][3]);
        *(s16x4*)(&scr[q * 32 + ((((kloc0 >> 3) ^ ((q >> 1) & 3)) << 3)) + (kloc0 & 7)]) = sv;
      }
    }
    bf16x8 pa[4];
    #pragma unroll
    for (int qt = 0; qt < 4; ++qt) {
      int q = qt * 16 + lr;
      pa[qt] = *(const bf16x8*)(&scr[q * 32 + ((lg ^ ((q >> 1) & 3)) << 3)]);
    }
    __builtin_amdgcn_s_setprio(1);
    #pragma unroll
    for (int dt = 0; dt < 2; ++dt)
      #pragma unroll
      for (int qt = 0; qt < 4; ++qt)
        o[dt][qt] = __builtin_amdgcn_mfma_f32_16x16x32_bf16(vb[dt * 2 + ks], pa[qt], o[dt][qt], 0, 0, 0);
    __builtin_amdgcn_s_setprio(0);
  }
  __syncthreads();                                // B2 (all As reads done)

  // -- Ol[q][c] (alias As), + v-bias (sum P = 1) ----------------------------
  #pragma unroll
  for (int dt = 0; dt < 2; ++dt) {
    int c0 = w * 32 + dt * 16 + lg * 4;
    float4 bv = *(const float4*)(qkv_b + 256 + c0);
    #pragma unroll
    for (int qt = 0; qt < 4; ++qt) {
      int q = qt * 16 + lr;
      s16x4 sv;
      sv[0] = f2bf(o[dt][qt][0] + bv.x); sv[1] = f2bf(o[dt][qt][1] + bv.y);
      sv[2] = f2bf(o[dt][qt][2] + bv.z); sv[3] = f2bf(o[dt][qt][3] + bv.w);
      *(s16x4*)(&Ol[q * 256 + ((((c0 >> 3) ^ (q & 7)) << 3)) + (c0 & 7)]) = sv;
    }
  }
  __syncthreads();                                // B3

  // -- proj: out^T strip = Wp_rows . O^T (swapped -> float4 stores) ---------
  f32x4 po[2][4] = {};
  const short* wpb = wp_b + (w * 32) * 256;
  #pragma unroll 2
  for (int kk = 0; kk < 8; ++kk) {
    bf16x8 of[4], wf2[2];
    #pragma unroll
    for (int qt = 0; qt < 4; ++qt) {
      int q = qt * 16 + lr;
      of[qt] = *(const bf16x8*)(&Ol[q * 256 + (((kk * 4 + lg) ^ (q & 7)) << 3)]);
    }
    #pragma unroll
    for (int mt = 0; mt < 2; ++mt)
      wf2[mt] = *(const bf16x8*)(wpb + (mt * 16 + lr) * 256 + kk * 32 + lg * 8);
    __builtin_amdgcn_s_setprio(1);
    #pragma unroll
    for (int mt = 0; mt < 2; ++mt)
      #pragma unroll
      for (int qt = 0; qt < 4; ++qt)
        po[mt][qt] = __builtin_amdgcn_mfma_f32_16x16x32_bf16(wf2[mt], of[qt], po[mt][qt], 0, 0, 0);
    __builtin_amdgcn_s_setprio(0);
  }
  float* od = out + (long)b * 49 * 256;
  #pragma unroll
  for (int mt = 0; mt < 2; ++mt) {
    int c0 = w * 32 + mt * 16 + lg * 4;
    float4 pb = *(const float4*)(proj_b + c0);
    #pragma unroll
    for (int qt = 0; qt < 4; ++qt) {
      int q = qt * 16 + lr;
      if (q < 49) {
        float4 ov;
        ov.x = po[mt][qt][0] + pb.x;
        ov.y = po[mt][qt][1] + pb.y;
        ov.z = po[mt][qt][2] + pb.z;
        ov.w = po[mt][qt][3] + pb.w;
        *(float4*)(od + q * 256 + c0) = ov;
      }
    }
  }
}

extern "C" void kernel_launch(void* const* d_in, const int* in_sizes, int n_in,
                              void* d_out, int out_size, void* d_ws, size_t ws_size,
                              hipStream_t stream) {
  const float* x      = (const float*)d_in[0];
  const float* qg     = (const float*)d_in[1];
  const float* qkv_w  = (const float*)d_in[2];
  const float* qkv_b  = (const float*)d_in[3];
  const float* proj_w = (const float*)d_in[4];
  const float* proj_b = (const float*)d_in[5];
  const float* table  = (const float*)d_in[6];
  float* out = (float*)d_out;

  char* ws = (char*)d_ws;                  // total scratch ~17.3 MB
  short* wv_b  = (short*)ws;               // 131072 B bf16 Wv [256][256]
  short* wp_b  = (short*)(ws + 131072);    // 131072 B bf16 Wp [256][256]
  short* wkT_b = (short*)(ws + 262144);    // 131072 B bf16 Wk^T [256 j][256 c]
  float* biasg = (float*)(ws + 393216);    // 131072 B f32 bias [8][64][64]
  short* qt_b  = (short*)(ws + 524288);    // 16777216 B bf16 q~ [64][8][64][256]

  const int prep1_total = 65536 * 3 + 32768;
  prep1<<<(prep1_total + 255) / 256, 256, 0, stream>>>(
      qkv_w, proj_w, table, wv_b, wp_b, wkT_b, biasg);
  prep2<<<dim3(4, 8, 64), 64, 0, stream>>>(qg, wkT_b, qt_b);
  fused_win<<<4096, 512, 0, stream>>>(x, qt_b, wv_b, wp_b, qkv_b, proj_b, biasg, out);
}